// Round 5
// baseline (353.363 us; speedup 1.0000x reference)
//
#include <hip/hip_runtime.h>
#include <hip/hip_bf16.h>

typedef __bf16 bf16x8 __attribute__((ext_vector_type(8)));
typedef __bf16 bf16x4 __attribute__((ext_vector_type(4)));
typedef float f32x4 __attribute__((ext_vector_type(4)));

#define B_N 1024
#define D_N 256
#define A_N 6
#define M_N 200000
#define K_N 16
#define H1_N 128
#define H2_N 64
#define NTILES 3125     // 200000 / 64
#define S_TILES 6       // prepass tiles per chunk
#define S_CHUNKS 32     // prepass chunks -> sample = 32*6*64 = 12288 rows
#define F_NC 128        // filter: m-chunk count (grid.x)
#define F_BY 4          // filter: b-groups of 256 cols (grid.y)
#define CAP 1024        // per-b survivor capacity
#define MEMCVT_BLKS (M_N / 4)

__device__ __forceinline__ float wred_sum(float v) {
#pragma unroll
  for (int o = 1; o < 64; o <<= 1) v += __shfl_xor(v, o, 64);
  return v;
}

// descending top-16 insert; compile-time indices only (stays in VGPRs)
__device__ __forceinline__ void topk_insert(float (&lst)[16], float v) {
  if (v <= lst[15]) return;
#pragma unroll
  for (int i = 0; i < 16; ++i) {
    bool gt = v > lst[i];
    float hi = gt ? v : lst[i];
    v = gt ? lst[i] : v;
    lst[i] = hi;
  }
}

__device__ __forceinline__ void load_lds16(const void* g, void* l) {
  __builtin_amdgcn_global_load_lds(
      (const __attribute__((address_space(1))) unsigned int*)g,
      (__attribute__((address_space(3))) unsigned int*)l, 16, 0, 0);
}

// ---------- fused: memcvt (blocks 0..49999) + forward model (blocks 50000+) -
__global__ __launch_bounds__(256) void prep_kernel(
    const float* __restrict__ mem, __bf16* __restrict__ memn,
    const float* __restrict__ z_t, const float* __restrict__ action,
    const float* __restrict__ z_t1, const float* __restrict__ sigma,
    const float* __restrict__ W1, const float* __restrict__ b1,
    const float* __restrict__ g1, const float* __restrict__ be1,
    const float* __restrict__ W2, const float* __restrict__ b2,
    const float* __restrict__ g2, const float* __restrict__ be2,
    const float* __restrict__ W3, const float* __restrict__ b3,
    float* __restrict__ out, __bf16* __restrict__ z_n) {
  __shared__ float s_inp[D_N + A_N];
  __shared__ float s_h1[H1_N];
  __shared__ float s_h2[H2_N];
  __shared__ float red[8];
  const int t = threadIdx.x;
  const int w = t >> 6;

  if (blockIdx.x < MEMCVT_BLKS) {
    // ---- mem row-norm + bf16 convert: 4 rows per block, wave per row ----
    const int l = t & 63;
    const size_t row = (size_t)blockIdx.x * 4 + w;
    const float4 v = ((const float4*)(mem + row * D_N))[l];
    float ss = wred_sum(v.x * v.x + v.y * v.y + v.z * v.z + v.w * v.w);
    const float inv = 1.0f / (sqrtf(ss) + 1e-8f);
    bf16x4 p;
    p[0] = (__bf16)(v.x * inv); p[1] = (__bf16)(v.y * inv);
    p[2] = (__bf16)(v.z * inv); p[3] = (__bf16)(v.w * inv);
    *(bf16x4*)(memn + row * D_N + l * 4) = p;
    return;
  }

  // ---- forward model for sample b ----
  const int b = blockIdx.x - MEMCVT_BLKS;

  float zv = z_t[b * D_N + t];
  s_inp[t] = zv;
  if (t < A_N) s_inp[D_N + t] = action[b * A_N + t];

  float ss = wred_sum(zv * zv);
  if ((t & 63) == 0) red[w] = ss;
  __syncthreads();
  float tot = red[0] + red[1] + red[2] + red[3];
  float invz = 1.0f / (sqrtf(tot) + 1e-8f);
  z_n[b * D_N + t] = (__bf16)(zv * invz);

  float y1 = 0.0f;
  if (t < H1_N) {
    y1 = b1[t];
    for (int k = 0; k < D_N + A_N; ++k) y1 += s_inp[k] * W1[k * H1_N + t];
  }
  __syncthreads();
  float s1 = wred_sum(t < H1_N ? y1 : 0.0f);
  float q1 = wred_sum(t < H1_N ? y1 * y1 : 0.0f);
  if ((t & 63) == 0) { red[w] = s1; red[4 + w] = q1; }
  __syncthreads();
  float S1 = red[0] + red[1] + red[2] + red[3];
  float Q1 = red[4] + red[5] + red[6] + red[7];
  float mu1 = S1 / (float)H1_N;
  float var1 = Q1 / (float)H1_N - mu1 * mu1;
  float rs1 = rsqrtf(var1 + 1e-5f);
  if (t < H1_N) {
    float xn = (y1 - mu1) * rs1;
    s_h1[t] = fmaxf(0.0f, xn * g1[t] + be1[t]);
  }
  __syncthreads();

  float y2 = 0.0f;
  if (t < H2_N) {
    y2 = b2[t];
    for (int k = 0; k < H1_N; ++k) y2 += s_h1[k] * W2[k * H2_N + t];
  }
  __syncthreads();
  float s2 = wred_sum(t < H2_N ? y2 : 0.0f);
  float q2 = wred_sum(t < H2_N ? y2 * y2 : 0.0f);
  if ((t & 63) == 0) { red[w] = s2; red[4 + w] = q2; }
  __syncthreads();
  float S2 = red[0] + red[1] + red[2] + red[3];
  float Q2 = red[4] + red[5] + red[6] + red[7];
  float mu2 = S2 / (float)H2_N;
  float var2 = Q2 / (float)H2_N - mu2 * mu2;
  float rs2 = rsqrtf(var2 + 1e-5f);
  if (t < H2_N) {
    float xn = (y2 - mu2) * rs2;
    s_h2[t] = fmaxf(0.0f, xn * g2[t] + be2[t]);
  }
  __syncthreads();

  float zp = b3[t];
  for (int k = 0; k < H2_N; ++k) zp += s_h2[k] * W3[k * D_N + t];
  float d = zp - z_t1[b * D_N + t];
  __syncthreads();
  float pe = wred_sum(d * d);
  if ((t & 63) == 0) red[w] = pe;
  __syncthreads();
  if (t == 0) {
    float PE = (red[0] + red[1] + red[2] + red[3]) / (float)D_N;
    out[B_N + b] = PE;
    float s6 = 0.0f;
    for (int i = 0; i < A_N; ++i) s6 += sigma[b * A_N + i];
    out[2 * B_N + b] = s6 / (float)A_N;
  }
}

// ---------------- prepass: exact top-16 over 12288-row sample ---------------
// grid (S_CHUNKS, 8) = 256 blocks; 512 thr = 8 waves x 16 b-cols.
__global__ __launch_bounds__(512) void prepass_kernel(
    const __bf16* __restrict__ memn, const __bf16* __restrict__ z_n,
    float* __restrict__ tcand) {
  __shared__ __bf16 tile[64 * 256];
  const int t = threadIdx.x;
  const int w = t >> 6;
  const int l = t & 63;
  const int c = l & 15;
  const int lg = l >> 4;
  const int brow = blockIdx.y * 128 + w * 16 + c;

  bf16x8 zf[8];
#pragma unroll
  for (int kc = 0; kc < 8; ++kc)
    zf[kc] = *(const bf16x8*)(z_n + brow * D_N + kc * 32 + lg * 8);

  float lst[16];
#pragma unroll
  for (int i = 0; i < 16; ++i) lst[i] = -3.0e38f;

  const int sr = t >> 3;
  const int sc = t & 7;
  char* tileb = (char*)tile;

  for (int tl = 0; tl < S_TILES; ++tl) {
    const int m0 = (blockIdx.x * S_TILES + tl) * 64;
#pragma unroll
    for (int i = 0; i < 4; ++i) {
      bf16x8 d = *(const bf16x8*)(memn + (size_t)(m0 + sr) * D_N + sc * 32 + i * 8);
      *(bf16x8*)(tileb + sr * 512 + ((sc * 64 + i * 16) ^ ((sr & 7) << 4))) = d;
    }
    __syncthreads();
#pragma unroll
    for (int mf = 0; mf < 4; ++mf) {
      const int row = mf * 16 + c;
      const int rsw = (row & 7) << 4;
      f32x4 acc = {0.f, 0.f, 0.f, 0.f};
#pragma unroll
      for (int kc = 0; kc < 8; ++kc) {
        const int inner = (kc * 64 + lg * 16) ^ rsw;
        bf16x8 a = *(const bf16x8*)(tileb + row * 512 + inner);
        acc = __builtin_amdgcn_mfma_f32_16x16x32_bf16(a, zf[kc], acc, 0, 0, 0);
      }
      topk_insert(lst, acc[0]);
      topk_insert(lst, acc[1]);
      topk_insert(lst, acc[2]);
      topk_insert(lst, acc[3]);
    }
    __syncthreads();
  }

  float mg[16];
#pragma unroll
  for (int r = 0; r < 16; ++r) {
    float h = lst[0];
    float g = fmaxf(h, __shfl_xor(h, 16, 64));
    g = fmaxf(g, __shfl_xor(g, 32, 64));
    unsigned long long bal = __ballot(h == g);
    unsigned long long grp = (bal >> c) & 0x0001000100010001ULL;
    int fs = __ffsll(grp) - 1;
    if ((lg << 4) == fs) {
#pragma unroll
      for (int i = 0; i < 15; ++i) lst[i] = lst[i + 1];
      lst[15] = -3.0e38f;
    }
    mg[r] = g;
  }
  if (l < 16) {
    float* dst = tcand + ((size_t)brow * S_CHUNKS + blockIdx.x) * 16;
#pragma unroll
    for (int i = 0; i < 16; i += 4) {
      float4 o = make_float4(mg[i], mg[i + 1], mg[i + 2], mg[i + 3]);
      *(float4*)(dst + i) = o;
    }
  }
}

// -------- tau: 16th-largest of the sample candidates (+ zero cnt) -----------
__global__ __launch_bounds__(64) void tau_kernel(
    const float* __restrict__ tcand, float* __restrict__ tau,
    int* __restrict__ cnt) {
  const int b = blockIdx.x;
  const int l = threadIdx.x;
  if (l == 0) cnt[b] = 0;
  float lst[16];
#pragma unroll
  for (int i = 0; i < 16; ++i) lst[i] = -3.0e38f;
  const float* cb = tcand + (size_t)b * (S_CHUNKS * 16);
#pragma unroll
  for (int k = 0; k < (S_CHUNKS * 16) / 64; ++k) topk_insert(lst, cb[k * 64 + l]);

  float g16 = -3.0e38f;
#pragma unroll
  for (int r = 0; r < K_N; ++r) {
    float h = lst[0];
    float g = h;
#pragma unroll
    for (int o = 1; o < 64; o <<= 1) g = fmaxf(g, __shfl_xor(g, o, 64));
    unsigned long long bal = __ballot(h == g);
    int winner = __ffsll(bal) - 1;
    if (l == winner) {
#pragma unroll
      for (int i = 0; i < 15; ++i) lst[i] = lst[i + 1];
      lst[15] = -3.0e38f;
    }
    g16 = g;
  }
  if (l == 0) tau[b] = g16;
}

// ---------------- filter: full GEMM + threshold push ------------------------
// grid (F_NC=128, F_BY=4); 256 thr = 4 waves x 64 b-cols (4 z-sets/wave).
// T4 counted-vmcnt pipeline: raw s_barrier, vmcnt(8) (never 0) -> next tile's
// 8 global_load_lds stay in flight across both barriers. Atomic pushes are
// always OLDER than the newest stage batch, so vmcnt(8) retires them too.
__global__ __launch_bounds__(256, 2) void filter_kernel(
    const __bf16* __restrict__ memn, const __bf16* __restrict__ z_n,
    const float* __restrict__ tau, int* __restrict__ cnt,
    float* __restrict__ candv) {
  __shared__ __bf16 tile[2][64 * 256];  // 2 x 32 KB, fragment-contiguous
  const int t = threadIdx.x;
  const int w = t >> 6;   // 0..3
  const int l = t & 63;
  const int c = l & 15;
  const int lg = l >> 4;
  const int bx = blockIdx.x;
  const int bbase = blockIdx.y * 256 + w * 64 + c;  // + s*16, s=0..3

  // z fragments, punned to f32x4 and pinned via opaque asm (no remat)
  f32x4 zr[4][8];
#pragma unroll
  for (int s = 0; s < 4; ++s)
#pragma unroll
    for (int kc = 0; kc < 8; ++kc)
      zr[s][kc] = *(const f32x4*)(z_n + (size_t)(bbase + s * 16) * D_N +
                                  kc * 32 + lg * 8);
#pragma unroll
  for (int s = 0; s < 4; ++s)
#pragma unroll
    for (int kc = 0; kc < 8; ++kc) asm volatile("" : "+v"(zr[s][kc]));

  float tauv[4];
#pragma unroll
  for (int s = 0; s < 4; ++s) tauv[s] = tau[bbase + s * 16];

  char* tileb = (char*)tile;
  // stage: thread handles frag-blocks w*8+i; global row = m0+w*16+c,
  // col elems i*32 + lg*8; LDS dest wave-uniform + lane*16 (m104 rule)
#define STAGE(buf, tl_)                                                       \
  {                                                                           \
    const __bf16* _g = memn + (size_t)((tl_) * 64 + w * 16 + c) * D_N + lg * 8; \
    char* _d = tileb + (buf) * 32768 + w * 8192;                              \
    _Pragma("unroll") for (int i = 0; i < 8; ++i)                             \
        load_lds16(_g + i * 32, _d + i * 1024);                               \
  }

  int cur = 0;
  STAGE(0, bx)
  STAGE(1, bx + F_NC)   // bx+F_NC <= 255 < NTILES always valid

  for (int tl = bx; tl < NTILES; tl += F_NC) {
    asm volatile("s_waitcnt vmcnt(8)" ::: "memory");
    __builtin_amdgcn_s_barrier();
    __builtin_amdgcn_sched_barrier(0);
    const char* curb = tileb + cur * 32768;
#pragma unroll
    for (int mf = 0; mf < 4; ++mf) {
      f32x4 acc0 = {0.f, 0.f, 0.f, 0.f};
      f32x4 acc1 = {0.f, 0.f, 0.f, 0.f};
      f32x4 acc2 = {0.f, 0.f, 0.f, 0.f};
      f32x4 acc3 = {0.f, 0.f, 0.f, 0.f};
#pragma unroll
      for (int kc = 0; kc < 8; ++kc) {
        bf16x8 a = *(const bf16x8*)(curb + (mf * 8 + kc) * 1024 + l * 16);
        acc0 = __builtin_amdgcn_mfma_f32_16x16x32_bf16(
            a, __builtin_bit_cast(bf16x8, zr[0][kc]), acc0, 0, 0, 0);
        acc1 = __builtin_amdgcn_mfma_f32_16x16x32_bf16(
            a, __builtin_bit_cast(bf16x8, zr[1][kc]), acc1, 0, 0, 0);
        acc2 = __builtin_amdgcn_mfma_f32_16x16x32_bf16(
            a, __builtin_bit_cast(bf16x8, zr[2][kc]), acc2, 0, 0, 0);
        acc3 = __builtin_amdgcn_mfma_f32_16x16x32_bf16(
            a, __builtin_bit_cast(bf16x8, zr[3][kc]), acc3, 0, 0, 0);
      }
#define PUSHS(accv, s)                                                        \
      _Pragma("unroll") for (int j = 0; j < 4; ++j) {                         \
        float v = (accv)[j];                                                  \
        if (v >= tauv[s]) {                                                   \
          int p = atomicAdd(&cnt[bbase + (s) * 16], 1);                       \
          if (p < CAP) candv[(size_t)(bbase + (s) * 16) * CAP + p] = v;       \
        }                                                                     \
      }
      PUSHS(acc0, 0) PUSHS(acc1, 1) PUSHS(acc2, 2) PUSHS(acc3, 3)
#undef PUSHS
    }
    asm volatile("s_waitcnt lgkmcnt(0)" ::: "memory");
    __builtin_amdgcn_s_barrier();   // WAR: all waves done reading buf[cur]
    int nx = tl + 2 * F_NC;
    if (nx >= NTILES) nx = bx;      // dummy stage keeps vmcnt math exact
    STAGE(cur, nx)
    cur ^= 1;
  }
#undef STAGE
}

// ---------------- final: exact top-16 of survivors + combine ----------------
__global__ __launch_bounds__(64) void final_kernel(
    const int* __restrict__ cnt, const float* __restrict__ candv,
    float* __restrict__ out) {
  const int b = blockIdx.x;
  const int l = threadIdx.x;
  const int n = min(cnt[b], CAP);
  float lst[16];
#pragma unroll
  for (int i = 0; i < 16; ++i) lst[i] = -3.0e38f;
  const float* cb = candv + (size_t)b * CAP;
  for (int k = l; k < n; k += 64) topk_insert(lst, cb[k]);

  float sum = 0.0f;
#pragma unroll
  for (int r = 0; r < K_N; ++r) {
    float h = lst[0];
    float g = h;
#pragma unroll
    for (int o = 1; o < 64; o <<= 1) g = fmaxf(g, __shfl_xor(g, o, 64));
    unsigned long long bal = __ballot(h == g);
    int winner = __ffsll(bal) - 1;
    if (l == winner) {
#pragma unroll
      for (int i = 0; i < 15; ++i) lst[i] = lst[i + 1];
      lst[15] = -3.0e38f;
    }
    sum += g;
  }
  float nov = 1.0f - sum / (float)K_N;
  nov = fminf(fmaxf(nov, 0.0f), 1.0f);
  if (l == 0) {
    float pe = out[B_N + b];
    float ep = out[2 * B_N + b];
    out[b] = pe + 0.5f * ep + 0.5f * nov;
    out[3 * B_N + b] = nov;
  }
}

extern "C" void kernel_launch(void* const* d_in, const int* in_sizes, int n_in,
                              void* d_out, int out_size, void* d_ws, size_t ws_size,
                              hipStream_t stream) {
  (void)in_sizes; (void)n_in; (void)out_size; (void)ws_size;
  const float* z_t    = (const float*)d_in[0];
  const float* action = (const float*)d_in[1];
  const float* z_t1   = (const float*)d_in[2];
  const float* sigma  = (const float*)d_in[3];
  const float* mem    = (const float*)d_in[4];
  const float* W1 = (const float*)d_in[5];
  const float* b1 = (const float*)d_in[6];
  const float* g1 = (const float*)d_in[7];
  const float* be1= (const float*)d_in[8];
  const float* W2 = (const float*)d_in[9];
  const float* b2 = (const float*)d_in[10];
  const float* g2 = (const float*)d_in[11];
  const float* be2= (const float*)d_in[12];
  const float* W3 = (const float*)d_in[13];
  const float* b3 = (const float*)d_in[14];
  float* out = (float*)d_out;

  // ws layout (~109.2 MB):
  char* ws = (char*)d_ws;
  __bf16* memn  = (__bf16*)ws;                          // 102,400,000 B
  __bf16* z_n   = (__bf16*)(ws + 102400256);            // 524,288 B
  float*  tcand = (float*)(ws + 102924544);             // 2,097,152 B
  float*  tau   = (float*)(ws + 105021696);             // 4,096 B
  int*    cnt   = (int*)(ws + 105025792);               // 4,096 B
  float*  candv = (float*)(ws + 105029888);             // 4,194,304 B

  prep_kernel<<<MEMCVT_BLKS + B_N, 256, 0, stream>>>(
      mem, memn, z_t, action, z_t1, sigma,
      W1, b1, g1, be1, W2, b2, g2, be2, W3, b3, out, z_n);
  prepass_kernel<<<dim3(S_CHUNKS, 8), 512, 0, stream>>>(memn, z_n, tcand);
  tau_kernel<<<B_N, 64, 0, stream>>>(tcand, tau, cnt);
  filter_kernel<<<dim3(F_NC, F_BY), 256, 0, stream>>>(memn, z_n, tau, cnt, candv);
  final_kernel<<<B_N, 64, 0, stream>>>(cnt, candv, out);
}

// Round 6
// 297.633 us; speedup vs baseline: 1.1872x; 1.1872x over previous
//
#include <hip/hip_runtime.h>
#include <hip/hip_bf16.h>

typedef __bf16 bf16x8 __attribute__((ext_vector_type(8)));
typedef __bf16 bf16x4 __attribute__((ext_vector_type(4)));
typedef float f32x4 __attribute__((ext_vector_type(4)));

#define B_N 1024
#define D_N 256
#define A_N 6
#define M_N 200000
#define K_N 16
#define H1_N 128
#define H2_N 64
#define NTILES 3125     // 200000 / 64
#define S_TILES 6       // prepass tiles per chunk
#define S_CHUNKS 32     // prepass chunks -> sample = 32*6*64 = 12288 rows
#define F_NC 128        // filter: m-chunk count (grid.x)
#define F_BY 4          // filter: b-groups of 256 cols (grid.y)
#define CAP 1024        // per-b survivor capacity
#define MEMCVT_BLKS (M_N / 4)

__device__ __forceinline__ float wred_sum(float v) {
#pragma unroll
  for (int o = 1; o < 64; o <<= 1) v += __shfl_xor(v, o, 64);
  return v;
}

// descending top-16 insert; compile-time indices only (stays in VGPRs)
__device__ __forceinline__ void topk_insert(float (&lst)[16], float v) {
  if (v <= lst[15]) return;
#pragma unroll
  for (int i = 0; i < 16; ++i) {
    bool gt = v > lst[i];
    float hi = gt ? v : lst[i];
    v = gt ? lst[i] : v;
    lst[i] = hi;
  }
}

__device__ __forceinline__ void load_lds16(const void* g, void* l) {
  __builtin_amdgcn_global_load_lds(
      (const __attribute__((address_space(1))) unsigned int*)g,
      (__attribute__((address_space(3))) unsigned int*)l, 16, 0, 0);
}

// ---------- fused: memcvt (blocks 0..49999) + forward model (blocks 50000+) -
__global__ __launch_bounds__(256) void prep_kernel(
    const float* __restrict__ mem, __bf16* __restrict__ memn,
    const float* __restrict__ z_t, const float* __restrict__ action,
    const float* __restrict__ z_t1, const float* __restrict__ sigma,
    const float* __restrict__ W1, const float* __restrict__ b1,
    const float* __restrict__ g1, const float* __restrict__ be1,
    const float* __restrict__ W2, const float* __restrict__ b2,
    const float* __restrict__ g2, const float* __restrict__ be2,
    const float* __restrict__ W3, const float* __restrict__ b3,
    float* __restrict__ out, __bf16* __restrict__ z_n) {
  __shared__ float s_inp[D_N + A_N];
  __shared__ float s_h1[H1_N];
  __shared__ float s_h2[H2_N];
  __shared__ float red[8];
  const int t = threadIdx.x;
  const int w = t >> 6;

  if (blockIdx.x < MEMCVT_BLKS) {
    // ---- mem row-norm + bf16 convert: 4 rows per block, wave per row ----
    const int l = t & 63;
    const size_t row = (size_t)blockIdx.x * 4 + w;
    const float4 v = ((const float4*)(mem + row * D_N))[l];
    float ss = wred_sum(v.x * v.x + v.y * v.y + v.z * v.z + v.w * v.w);
    const float inv = 1.0f / (sqrtf(ss) + 1e-8f);
    bf16x4 p;
    p[0] = (__bf16)(v.x * inv); p[1] = (__bf16)(v.y * inv);
    p[2] = (__bf16)(v.z * inv); p[3] = (__bf16)(v.w * inv);
    *(bf16x4*)(memn + row * D_N + l * 4) = p;
    return;
  }

  // ---- forward model for sample b ----
  const int b = blockIdx.x - MEMCVT_BLKS;

  float zv = z_t[b * D_N + t];
  s_inp[t] = zv;
  if (t < A_N) s_inp[D_N + t] = action[b * A_N + t];

  float ss = wred_sum(zv * zv);
  if ((t & 63) == 0) red[w] = ss;
  __syncthreads();
  float tot = red[0] + red[1] + red[2] + red[3];
  float invz = 1.0f / (sqrtf(tot) + 1e-8f);
  z_n[b * D_N + t] = (__bf16)(zv * invz);

  float y1 = 0.0f;
  if (t < H1_N) {
    y1 = b1[t];
    for (int k = 0; k < D_N + A_N; ++k) y1 += s_inp[k] * W1[k * H1_N + t];
  }
  __syncthreads();
  float s1 = wred_sum(t < H1_N ? y1 : 0.0f);
  float q1 = wred_sum(t < H1_N ? y1 * y1 : 0.0f);
  if ((t & 63) == 0) { red[w] = s1; red[4 + w] = q1; }
  __syncthreads();
  float S1 = red[0] + red[1] + red[2] + red[3];
  float Q1 = red[4] + red[5] + red[6] + red[7];
  float mu1 = S1 / (float)H1_N;
  float var1 = Q1 / (float)H1_N - mu1 * mu1;
  float rs1 = rsqrtf(var1 + 1e-5f);
  if (t < H1_N) {
    float xn = (y1 - mu1) * rs1;
    s_h1[t] = fmaxf(0.0f, xn * g1[t] + be1[t]);
  }
  __syncthreads();

  float y2 = 0.0f;
  if (t < H2_N) {
    y2 = b2[t];
    for (int k = 0; k < H1_N; ++k) y2 += s_h1[k] * W2[k * H2_N + t];
  }
  __syncthreads();
  float s2 = wred_sum(t < H2_N ? y2 : 0.0f);
  float q2 = wred_sum(t < H2_N ? y2 * y2 : 0.0f);
  if ((t & 63) == 0) { red[w] = s2; red[4 + w] = q2; }
  __syncthreads();
  float S2 = red[0] + red[1] + red[2] + red[3];
  float Q2 = red[4] + red[5] + red[6] + red[7];
  float mu2 = S2 / (float)H2_N;
  float var2 = Q2 / (float)H2_N - mu2 * mu2;
  float rs2 = rsqrtf(var2 + 1e-5f);
  if (t < H2_N) {
    float xn = (y2 - mu2) * rs2;
    s_h2[t] = fmaxf(0.0f, xn * g2[t] + be2[t]);
  }
  __syncthreads();

  float zp = b3[t];
  for (int k = 0; k < H2_N; ++k) zp += s_h2[k] * W3[k * D_N + t];
  float d = zp - z_t1[b * D_N + t];
  __syncthreads();
  float pe = wred_sum(d * d);
  if ((t & 63) == 0) red[w] = pe;
  __syncthreads();
  if (t == 0) {
    float PE = (red[0] + red[1] + red[2] + red[3]) / (float)D_N;
    out[B_N + b] = PE;
    float s6 = 0.0f;
    for (int i = 0; i < A_N; ++i) s6 += sigma[b * A_N + i];
    out[2 * B_N + b] = s6 / (float)A_N;
  }
}

// ---------------- prepass: exact top-16 over 12288-row sample ---------------
// grid (S_CHUNKS, 8) = 256 blocks; 512 thr = 8 waves x 16 b-cols.
__global__ __launch_bounds__(512) void prepass_kernel(
    const __bf16* __restrict__ memn, const __bf16* __restrict__ z_n,
    float* __restrict__ tcand) {
  __shared__ __bf16 tile[64 * 256];
  const int t = threadIdx.x;
  const int w = t >> 6;
  const int l = t & 63;
  const int c = l & 15;
  const int lg = l >> 4;
  const int brow = blockIdx.y * 128 + w * 16 + c;

  bf16x8 zf[8];
#pragma unroll
  for (int kc = 0; kc < 8; ++kc)
    zf[kc] = *(const bf16x8*)(z_n + brow * D_N + kc * 32 + lg * 8);

  float lst[16];
#pragma unroll
  for (int i = 0; i < 16; ++i) lst[i] = -3.0e38f;

  const int sr = t >> 3;
  const int sc = t & 7;
  char* tileb = (char*)tile;

  for (int tl = 0; tl < S_TILES; ++tl) {
    const int m0 = (blockIdx.x * S_TILES + tl) * 64;
#pragma unroll
    for (int i = 0; i < 4; ++i) {
      bf16x8 d = *(const bf16x8*)(memn + (size_t)(m0 + sr) * D_N + sc * 32 + i * 8);
      *(bf16x8*)(tileb + sr * 512 + ((sc * 64 + i * 16) ^ ((sr & 7) << 4))) = d;
    }
    __syncthreads();
#pragma unroll
    for (int mf = 0; mf < 4; ++mf) {
      const int row = mf * 16 + c;
      const int rsw = (row & 7) << 4;
      f32x4 acc = {0.f, 0.f, 0.f, 0.f};
#pragma unroll
      for (int kc = 0; kc < 8; ++kc) {
        const int inner = (kc * 64 + lg * 16) ^ rsw;
        bf16x8 a = *(const bf16x8*)(tileb + row * 512 + inner);
        acc = __builtin_amdgcn_mfma_f32_16x16x32_bf16(a, zf[kc], acc, 0, 0, 0);
      }
      topk_insert(lst, acc[0]);
      topk_insert(lst, acc[1]);
      topk_insert(lst, acc[2]);
      topk_insert(lst, acc[3]);
    }
    __syncthreads();
  }

  float mg[16];
#pragma unroll
  for (int r = 0; r < 16; ++r) {
    float h = lst[0];
    float g = fmaxf(h, __shfl_xor(h, 16, 64));
    g = fmaxf(g, __shfl_xor(g, 32, 64));
    unsigned long long bal = __ballot(h == g);
    unsigned long long grp = (bal >> c) & 0x0001000100010001ULL;
    int fs = __ffsll(grp) - 1;
    if ((lg << 4) == fs) {
#pragma unroll
      for (int i = 0; i < 15; ++i) lst[i] = lst[i + 1];
      lst[15] = -3.0e38f;
    }
    mg[r] = g;
  }
  if (l < 16) {
    float* dst = tcand + ((size_t)brow * S_CHUNKS + blockIdx.x) * 16;
#pragma unroll
    for (int i = 0; i < 16; i += 4) {
      float4 o = make_float4(mg[i], mg[i + 1], mg[i + 2], mg[i + 3]);
      *(float4*)(dst + i) = o;
    }
  }
}

// -------- tau: 16th-largest of the sample candidates (+ zero cnt) -----------
__global__ __launch_bounds__(64) void tau_kernel(
    const float* __restrict__ tcand, float* __restrict__ tau,
    int* __restrict__ cnt) {
  const int b = blockIdx.x;
  const int l = threadIdx.x;
  if (l == 0) cnt[b] = 0;
  float lst[16];
#pragma unroll
  for (int i = 0; i < 16; ++i) lst[i] = -3.0e38f;
  const float* cb = tcand + (size_t)b * (S_CHUNKS * 16);
#pragma unroll
  for (int k = 0; k < (S_CHUNKS * 16) / 64; ++k) topk_insert(lst, cb[k * 64 + l]);

  float g16 = -3.0e38f;
#pragma unroll
  for (int r = 0; r < K_N; ++r) {
    float h = lst[0];
    float g = h;
#pragma unroll
    for (int o = 1; o < 64; o <<= 1) g = fmaxf(g, __shfl_xor(g, o, 64));
    unsigned long long bal = __ballot(h == g);
    int winner = __ffsll(bal) - 1;
    if (l == winner) {
#pragma unroll
      for (int i = 0; i < 15; ++i) lst[i] = lst[i + 1];
      lst[15] = -3.0e38f;
    }
    g16 = g;
  }
  if (l == 0) tau[b] = g16;
}

// ---------------- filter: full GEMM + threshold stash -----------------------
// grid (F_NC=128, F_BY=4); 256 thr = 4 waves x 64 b-cols (4 z-sets/wave).
// Steady-state loop has NO global atomics: survivors go to per-thread register
// stashes (2 slots per z-set; overflow -> rare direct push). One deferred
// atomic flush per (thread, z-set) after the loop. This keeps the counted
// vmcnt(8) prefetch pipeline intact (atomicAdd w/ return forces vmcnt(0) =
// full queue drain -- the R4/R5 killer).
__global__ __launch_bounds__(256, 2) void filter_kernel(
    const __bf16* __restrict__ memn, const __bf16* __restrict__ z_n,
    const float* __restrict__ tau, int* __restrict__ cnt,
    float* __restrict__ candv) {
  __shared__ __bf16 tile[2][64 * 256];  // 2 x 32 KB, fragment-contiguous
  const int t = threadIdx.x;
  const int w = t >> 6;   // 0..3
  const int l = t & 63;
  const int c = l & 15;
  const int lg = l >> 4;
  const int bx = blockIdx.x;
  const int bbase = blockIdx.y * 256 + w * 64 + c;  // + s*16, s=0..3

  // z fragments, punned to f32x4 and pinned via opaque asm (no remat)
  f32x4 zr[4][8];
#pragma unroll
  for (int s = 0; s < 4; ++s)
#pragma unroll
    for (int kc = 0; kc < 8; ++kc)
      zr[s][kc] = *(const f32x4*)(z_n + (size_t)(bbase + s * 16) * D_N +
                                  kc * 32 + lg * 8);
#pragma unroll
  for (int s = 0; s < 4; ++s)
#pragma unroll
    for (int kc = 0; kc < 8; ++kc) asm volatile("" : "+v"(zr[s][kc]));

  float tauv[4];
#pragma unroll
  for (int s = 0; s < 4; ++s) tauv[s] = tau[bbase + s * 16];

  // per-thread survivor stash (static indices only)
  float st0[4], st1[4];
  int nss[4];
#pragma unroll
  for (int s = 0; s < 4; ++s) { st0[s] = 0.f; st1[s] = 0.f; nss[s] = 0; }

  char* tileb = (char*)tile;
#define STAGE(buf, tl_)                                                       \
  {                                                                           \
    const __bf16* _g = memn + (size_t)((tl_) * 64 + w * 16 + c) * D_N + lg * 8; \
    char* _d = tileb + (buf) * 32768 + w * 8192;                              \
    _Pragma("unroll") for (int i = 0; i < 8; ++i)                             \
        load_lds16(_g + i * 32, _d + i * 1024);                               \
  }

  int cur = 0;
  STAGE(0, bx)
  STAGE(1, bx + F_NC)   // bx+F_NC <= 255 < NTILES always valid

  for (int tl = bx; tl < NTILES; tl += F_NC) {
    asm volatile("s_waitcnt vmcnt(8)" ::: "memory");
    __builtin_amdgcn_s_barrier();
    __builtin_amdgcn_sched_barrier(0);
    const char* curb = tileb + cur * 32768;
#pragma unroll
    for (int mf = 0; mf < 4; ++mf) {
      f32x4 acc0 = {0.f, 0.f, 0.f, 0.f};
      f32x4 acc1 = {0.f, 0.f, 0.f, 0.f};
      f32x4 acc2 = {0.f, 0.f, 0.f, 0.f};
      f32x4 acc3 = {0.f, 0.f, 0.f, 0.f};
#pragma unroll
      for (int kc = 0; kc < 8; ++kc) {
        bf16x8 a = *(const bf16x8*)(curb + (mf * 8 + kc) * 1024 + l * 16);
        acc0 = __builtin_amdgcn_mfma_f32_16x16x32_bf16(
            a, __builtin_bit_cast(bf16x8, zr[0][kc]), acc0, 0, 0, 0);
        acc1 = __builtin_amdgcn_mfma_f32_16x16x32_bf16(
            a, __builtin_bit_cast(bf16x8, zr[1][kc]), acc1, 0, 0, 0);
        acc2 = __builtin_amdgcn_mfma_f32_16x16x32_bf16(
            a, __builtin_bit_cast(bf16x8, zr[2][kc]), acc2, 0, 0, 0);
        acc3 = __builtin_amdgcn_mfma_f32_16x16x32_bf16(
            a, __builtin_bit_cast(bf16x8, zr[3][kc]), acc3, 0, 0, 0);
      }
#define STASH(accv, s)                                                        \
      _Pragma("unroll") for (int j = 0; j < 4; ++j) {                         \
        float v = (accv)[j];                                                  \
        if (v >= tauv[s]) {                                                   \
          if (nss[s] == 0) { st0[s] = v; nss[s] = 1; }                        \
          else if (nss[s] == 1) { st1[s] = v; nss[s] = 2; }                   \
          else {  /* rare overflow: direct push */                            \
            int p = atomicAdd(&cnt[bbase + (s) * 16], 1);                     \
            if (p < CAP) candv[(size_t)(bbase + (s) * 16) * CAP + p] = v;     \
          }                                                                   \
        }                                                                     \
      }
      STASH(acc0, 0) STASH(acc1, 1) STASH(acc2, 2) STASH(acc3, 3)
#undef STASH
    }
    asm volatile("s_waitcnt lgkmcnt(0)" ::: "memory");
    __builtin_amdgcn_s_barrier();   // WAR: all waves done reading buf[cur]
    int nx = tl + 2 * F_NC;
    if (nx >= NTILES) nx = bx;      // dummy stage keeps vmcnt math exact
    STAGE(cur, nx)
    cur ^= 1;
  }
#undef STAGE

  // deferred flush: one atomic per (thread, z-set), all at kernel end
#pragma unroll
  for (int s = 0; s < 4; ++s) {
    if (nss[s] > 0) {
      const int bb = bbase + s * 16;
      int p = atomicAdd(&cnt[bb], nss[s]);
      if (p < CAP) candv[(size_t)bb * CAP + p] = st0[s];
      if (nss[s] == 2 && p + 1 < CAP) candv[(size_t)bb * CAP + p + 1] = st1[s];
    }
  }
}

// ---------------- final: exact top-16 of survivors + combine ----------------
__global__ __launch_bounds__(64) void final_kernel(
    const int* __restrict__ cnt, const float* __restrict__ candv,
    float* __restrict__ out) {
  const int b = blockIdx.x;
  const int l = threadIdx.x;
  const int n = min(cnt[b], CAP);
  float lst[16];
#pragma unroll
  for (int i = 0; i < 16; ++i) lst[i] = -3.0e38f;
  const float* cb = candv + (size_t)b * CAP;
  for (int k = l; k < n; k += 64) topk_insert(lst, cb[k]);

  float sum = 0.0f;
#pragma unroll
  for (int r = 0; r < K_N; ++r) {
    float h = lst[0];
    float g = h;
#pragma unroll
    for (int o = 1; o < 64; o <<= 1) g = fmaxf(g, __shfl_xor(g, o, 64));
    unsigned long long bal = __ballot(h == g);
    int winner = __ffsll(bal) - 1;
    if (l == winner) {
#pragma unroll
      for (int i = 0; i < 15; ++i) lst[i] = lst[i + 1];
      lst[15] = -3.0e38f;
    }
    sum += g;
  }
  float nov = 1.0f - sum / (float)K_N;
  nov = fminf(fmaxf(nov, 0.0f), 1.0f);
  if (l == 0) {
    float pe = out[B_N + b];
    float ep = out[2 * B_N + b];
    out[b] = pe + 0.5f * ep + 0.5f * nov;
    out[3 * B_N + b] = nov;
  }
}

extern "C" void kernel_launch(void* const* d_in, const int* in_sizes, int n_in,
                              void* d_out, int out_size, void* d_ws, size_t ws_size,
                              hipStream_t stream) {
  (void)in_sizes; (void)n_in; (void)out_size; (void)ws_size;
  const float* z_t    = (const float*)d_in[0];
  const float* action = (const float*)d_in[1];
  const float* z_t1   = (const float*)d_in[2];
  const float* sigma  = (const float*)d_in[3];
  const float* mem    = (const float*)d_in[4];
  const float* W1 = (const float*)d_in[5];
  const float* b1 = (const float*)d_in[6];
  const float* g1 = (const float*)d_in[7];
  const float* be1= (const float*)d_in[8];
  const float* W2 = (const float*)d_in[9];
  const float* b2 = (const float*)d_in[10];
  const float* g2 = (const float*)d_in[11];
  const float* be2= (const float*)d_in[12];
  const float* W3 = (const float*)d_in[13];
  const float* b3 = (const float*)d_in[14];
  float* out = (float*)d_out;

  // ws layout (~109.2 MB):
  char* ws = (char*)d_ws;
  __bf16* memn  = (__bf16*)ws;                          // 102,400,000 B
  __bf16* z_n   = (__bf16*)(ws + 102400256);            // 524,288 B
  float*  tcand = (float*)(ws + 102924544);             // 2,097,152 B
  float*  tau   = (float*)(ws + 105021696);             // 4,096 B
  int*    cnt   = (int*)(ws + 105025792);               // 4,096 B
  float*  candv = (float*)(ws + 105029888);             // 4,194,304 B

  prep_kernel<<<MEMCVT_BLKS + B_N, 256, 0, stream>>>(
      mem, memn, z_t, action, z_t1, sigma,
      W1, b1, g1, be1, W2, b2, g2, be2, W3, b3, out, z_n);
  prepass_kernel<<<dim3(S_CHUNKS, 8), 512, 0, stream>>>(memn, z_n, tcand);
  tau_kernel<<<B_N, 64, 0, stream>>>(tcand, tau, cnt);
  filter_kernel<<<dim3(F_NC, F_BY), 256, 0, stream>>>(memn, z_n, tau, cnt, candv);
  final_kernel<<<B_N, 64, 0, stream>>>(cnt, candv, out);
}